// Round 4
// baseline (480.174 us; speedup 1.0000x reference)
//
#include <hip/hip_runtime.h>

// B=32, T=2048, E=128, fp32. Gram restructure, v3 (occupancy fix):
//   KA: 512 thr/block (8 waves, 2 blocks/CU -> 4 waves/SIMD), 4x8 reg tile,
//       BK=16 (8 barriers).  R3 measured: 256thr/8x8/BK=8 = 2 waves/SIMD ->
//       VALUBusy 31% = latency-bound at 48.8us vs 13.7us FMA floor.
//   KB: one block per (b, 2 chunks): reads M partials ONCE, computes both
//       c1-part (row dot sx2) and c2-part (col fma sx1). grid (32,8).
//   KC: sums 8 c-partials on load; et += c.U (U read once). KD softmax. KE o-pass.

#define B_ 32
#define T_ 2048
#define E_ 128
#define EV (E_/4)
#define INV_T (1.0f/2048.0f)
#define RC 128      // rows per KA block
#define BK 16       // k-step rows
#define NSTEP (RC/BK)
#define NG (T_/RC)  // 16 chunks

// ws float offsets (every slot written before read -> no zeroing needed)
#define WS_PSX1 0                      // B*NG*E = 65536
#define WS_PSX2 65536                  // B*NG*E
#define WS_PM   131072                 // B*NG*E*E = 8388608 (33.5MB)
#define WS_ET1  8519680                // B*T
#define WS_ET2  8585216                // B*T
#define WS_C1   8650752                // B*8*E = 32768 (8-way partials)
#define WS_C2   8683520                // B*8*E

__device__ __forceinline__ float dot4(float4 a, float4 b) {
    return a.x*b.x + a.y*b.y + a.z*b.z + a.w*b.w;
}
__device__ __forceinline__ void fma4(float4& a, float s, const float4 v) {
    a.x += s*v.x; a.y += s*v.y; a.z += s*v.z; a.w += s*v.w;
}
__device__ __forceinline__ void add4(float4& a, const float4 v) {
    a.x += v.x; a.y += v.y; a.z += v.z; a.w += v.w;
}

// ---- KA: Gram partial + psx partial + xw logit base, one x pass ----
__global__ __launch_bounds__(512, 4)
void ka_gram(const float* __restrict__ x1, const float* __restrict__ x2,
             const float* __restrict__ W1, const float* __restrict__ b1,
             const float* __restrict__ W2, const float* __restrict__ b2,
             float* __restrict__ ws) {
    __shared__ float4 sbuf[2][2][BK][32];   // [dbuf][tensor][row][swz slot] 32KB
    __shared__ float4 sW[2][32];
    __shared__ float4 spx[1024];            // psx epilogue scratch 16KB
    const int b = blockIdx.x, g = blockIdx.y, tid = threadIdx.x;
    if (tid < 64) sW[tid>>5][tid&31] = ((const float4*)((tid<32) ? W1 : W2))[tid&31];
    __syncthreads();   // sW visible to ALL waves before prologue xw dot

    // staging role: tensor / row-in-chunk(16) / col-pair(16)
    const int ten = tid>>8, rem = tid&255, row = rem>>4, q = rem&15;
    // compute role: 4x8 tile at (e=ty*4.., f=tx*8..)
    const int ty = tid>>4, tx = tid&15;
    const int sA = (ty>>1) | ((ty&1)<<4);   // swizzled slot of logical c4=ty

    const float4* xg = (const float4*)(ten ? x2 : x1) + ((size_t)b*T_ + g*RC)*EV;
    const int loff = row*EV + 2*q;          // per-step load offset (float4)

    float* etp = ws + (ten ? WS_ET2 : WS_ET1) + (size_t)b*T_;
    const float* bias = ten ? b2 : b1;

    float4 acc[8];
    #pragma unroll
    for (int i = 0; i < 8; ++i) acc[i] = make_float4(0.f,0.f,0.f,0.f);
    float4 psa = {0,0,0,0}, psb = {0,0,0,0};

    // prologue: chunk 0 -> sbuf[0], plus its psx/xw
    {
        float4 n0 = xg[loff], n1 = xg[loff + 1];
        add4(psa, n0); add4(psb, n1);
        float d = dot4(n0, sW[ten][2*q]) + dot4(n1, sW[ten][2*q+1]);
        d += __shfl_xor(d, 1); d += __shfl_xor(d, 2);
        d += __shfl_xor(d, 4); d += __shfl_xor(d, 8);
        if (q == 0) { int t = g*RC + row; etp[t] = d + bias[t]; }
        sbuf[0][ten][row][q]      = n0;     // swz(2q)=q
        sbuf[0][ten][row][16 + q] = n1;     // swz(2q+1)=16+q
    }
    __syncthreads();

    for (int k = 0; k < NSTEP; ++k) {
        const int p = k & 1;
        float4 m0, m1;
        if (k < NSTEP-1) {
            m0 = xg[(k+1)*BK*EV + loff];
            m1 = xg[(k+1)*BK*EV + loff + 1];
        }
        #pragma unroll
        for (int t = 0; t < BK; ++t) {
            const float4 a   = sbuf[p][1][t][sA];        // x2 e-frag (4 rows)
            const float4 bv0 = sbuf[p][0][t][tx];        // x1 f-frag lo
            const float4 bv1 = sbuf[p][0][t][16 + tx];   // x1 f-frag hi
            fma4(acc[0], a.x, bv0); fma4(acc[1], a.x, bv1);
            fma4(acc[2], a.y, bv0); fma4(acc[3], a.y, bv1);
            fma4(acc[4], a.z, bv0); fma4(acc[5], a.z, bv1);
            fma4(acc[6], a.w, bv0); fma4(acc[7], a.w, bv1);
        }
        if (k < NSTEP-1) {
            add4(psa, m0); add4(psb, m1);
            float d = dot4(m0, sW[ten][2*q]) + dot4(m1, sW[ten][2*q+1]);
            d += __shfl_xor(d, 1); d += __shfl_xor(d, 2);
            d += __shfl_xor(d, 4); d += __shfl_xor(d, 8);
            if (q == 0) { int t = g*RC + (k+1)*BK + row; etp[t] = d + bias[t]; }
            sbuf[1-p][ten][row][q]      = m0;
            sbuf[1-p][ten][row][16 + q] = m1;
        }
        __syncthreads();
    }

    // M partial: logical layout [e][f4], e row stride 32 float4
    float4* pMW = (float4*)(ws + WS_PM) + (size_t)(b*NG + g)*4096;
    #pragma unroll
    for (int i = 0; i < 4; ++i) {
        pMW[(ty*4 + i)*32 + 2*tx + 0] = acc[2*i+0];
        pMW[(ty*4 + i)*32 + 2*tx + 1] = acc[2*i+1];
    }

    // psx partial: reduce over the 16 row-owners per (tensor, col-quad)
    spx[tid] = psa; spx[512 + tid] = psb;
    __syncthreads();
    if (tid < 64) {
        const int t2 = tid>>5, j = tid&31;
        const int base = (j&1)*512 + t2*256 + (j>>1);
        float4 s = {0,0,0,0};
        #pragma unroll
        for (int r = 0; r < 16; ++r) add4(s, spx[base + r*16]);
        ((float4*)(ws + (t2 ? WS_PSX2 : WS_PSX1)))[(size_t)(b*NG + g)*32 + j] = s;
    }
}

// ---- KB: sx reduce + per-2-chunk partials of BOTH c1 (M.sx2) and c2 (M^T.sx1).
//      M partials read exactly once. grid (B, 8). ----
__global__ __launch_bounds__(256)
void kb_c(float* __restrict__ ws) {
    __shared__ float4 ssx1v[32], ssx2v[32];
    __shared__ float4 c2p[8][32];
    const int b = blockIdx.x, gs = blockIdx.y, tid = threadIdx.x;
    float* ssx1 = (float*)ssx1v;
    float* ssx2 = (float*)ssx2v;
    if (tid < 128) {
        float s = 0.f;
        #pragma unroll
        for (int g = 0; g < NG; ++g) s += ws[WS_PSX2 + (size_t)(b*NG + g)*E_ + tid];
        ssx2[tid] = s;
    } else {
        float s = 0.f;
        #pragma unroll
        for (int g = 0; g < NG; ++g) s += ws[WS_PSX1 + (size_t)(b*NG + g)*E_ + (tid-128)];
        ssx1[tid-128] = s;
    }
    __syncthreads();
    const int hw = tid>>5, j = tid&31;
    const float4* pM4 = (const float4*)(ws + WS_PM) + (size_t)b*NG*4096;
    const float4 sxj = ssx2v[j];
    float4 c2a = {0,0,0,0};
    #pragma unroll
    for (int r = 0; r < 16; ++r) {
        const int e = hw*16 + r;
        const float s1 = ssx1[e];
        float ca = 0.f;
        #pragma unroll
        for (int g2 = 0; g2 < 2; ++g2) {
            float4 v = pM4[(size_t)(gs*2 + g2)*4096 + e*32 + j];
            ca += dot4(v, sxj);
            fma4(c2a, s1, v);
        }
        #pragma unroll
        for (int m = 1; m <= 16; m <<= 1) ca += __shfl_xor(ca, m);
        if (j == 0) ws[WS_C1 + (size_t)(b*8 + gs)*E_ + e] = ca * INV_T;
    }
    c2p[hw][j] = c2a;
    __syncthreads();
    if (tid < 128) {
        float s = 0.f;
        #pragma unroll
        for (int h = 0; h < 8; ++h) s += ((const float*)c2p)[h*128 + tid];
        ws[WS_C2 + (size_t)(b*8 + gs)*E_ + tid] = s * INV_T;
    }
}

// ---- KC: et += c.U, t-chunked (128 t / block); c = sum of 8 partials, in LDS ----
__global__ __launch_bounds__(256)
void kc_etU(const float* __restrict__ U1, const float* __restrict__ U2,
            float* __restrict__ ws) {
    __shared__ float s_c[B_][E_];          // 16 KB
    const int ch = blockIdx.x, sel = blockIdx.y, tid = threadIdx.x;
    const float4* c4g = (const float4*)(ws + (sel ? WS_C2 : WS_C1));
    float4* s_c4 = (float4*)&s_c[0][0];
    #pragma unroll
    for (int i = 0; i < 4; ++i) {
        const int idx = tid + 256*i;              // b*32 + e4
        const int base = (idx & ~31)*8 + (idx & 31);   // b*256 + e4
        float4 s = {0,0,0,0};
        #pragma unroll
        for (int gs = 0; gs < 8; ++gs) add4(s, c4g[base + gs*32]);
        s_c4[idx] = s;
    }
    __syncthreads();
    const float4* U4 = (const float4*)(sel ? U2 : U1);   // E x T/4
    const int c4i = tid&31, bg = tid>>5;                 // 8 groups of 4 batches
    float4 acc[4];
    #pragma unroll
    for (int q = 0; q < 4; ++q) acc[q] = make_float4(0.f,0.f,0.f,0.f);
    #pragma unroll 4
    for (int e = 0; e < E_; ++e) {
        const float4 u = U4[(size_t)e*(T_/4) + ch*32 + c4i];
        fma4(acc[0], s_c[bg*4+0][e], u);
        fma4(acc[1], s_c[bg*4+1][e], u);
        fma4(acc[2], s_c[bg*4+2][e], u);
        fma4(acc[3], s_c[bg*4+3][e], u);
    }
    float4* et4 = (float4*)(ws + (sel ? WS_ET2 : WS_ET1));
    #pragma unroll
    for (int q = 0; q < 4; ++q) {
        const int bb = bg*4 + q;
        const size_t idx = (size_t)bb*(T_/4) + ch*32 + c4i;
        float4 v = et4[idx];          // xw base from KA
        add4(v, acc[q]);
        et4[idx] = v;
    }
}

// ---- KD: softmax over t -> probs in place; zero out for KE's atomics ----
__global__ __launch_bounds__(512)
void kd_softmax(float* __restrict__ ws, float* __restrict__ out) {
    __shared__ float red[512];
    const int b = blockIdx.x, sel = blockIdx.y, tid = threadIdx.x;
    float4* et4 = (float4*)(ws + (sel ? WS_ET2 : WS_ET1) + (size_t)b*T_);
    float4 v = et4[tid];
    if (tid < E_) out[b*2*E_ + sel*E_ + tid] = 0.f;
    float m = fmaxf(fmaxf(v.x, v.y), fmaxf(v.z, v.w));
    red[tid] = m; __syncthreads();
    for (int s = 256; s > 0; s >>= 1) {
        if (tid < s) red[tid] = fmaxf(red[tid], red[tid+s]);
        __syncthreads();
    }
    m = red[0]; __syncthreads();
    float4 e4;
    e4.x = __expf(v.x - m); e4.y = __expf(v.y - m);
    e4.z = __expf(v.z - m); e4.w = __expf(v.w - m);
    red[tid] = e4.x + e4.y + e4.z + e4.w;
    __syncthreads();
    for (int s = 256; s > 0; s >>= 1) {
        if (tid < s) red[tid] += red[tid+s];
        __syncthreads();
    }
    const float il = 1.f / red[0];
    e4.x *= il; e4.y *= il; e4.z *= il; e4.w *= il;
    et4[tid] = e4;
}

// ---- KE: o = sum_t at[t]*x[t,:] (proven) ----
__global__ __launch_bounds__(256)
void ke_out(const float* __restrict__ x1, const float* __restrict__ x2,
            const float* __restrict__ ws, float* __restrict__ out) {
    __shared__ float4 s_r1[256], s_r2[256];
    __shared__ float s_p1[128], s_p2[128];
    const int b = blockIdx.x, g = blockIdx.y, tid = threadIdx.x;
    const float* pr1 = ws + WS_ET1 + (size_t)b*T_ + g*128;
    const float* pr2 = ws + WS_ET2 + (size_t)b*T_ + g*128;
    if (tid < 128) s_p1[tid] = pr1[tid];
    else           s_p2[tid - 128] = pr2[tid - 128];
    __syncthreads();
    const float4* p1 = (const float4*)x1 + ((size_t)b*T_ + g*128)*EV;
    const float4* p2 = (const float4*)x2 + ((size_t)b*T_ + g*128)*EV;
    const int rg = tid >> 5, q = tid & 31;
    float4 a1 = {0,0,0,0}, a2 = {0,0,0,0};
    #pragma unroll
    for (int i = 0; i < 16; ++i) {
        int r = i*8 + rg;
        fma4(a1, s_p1[r], p1[r*EV + q]);
        fma4(a2, s_p2[r], p2[r*EV + q]);
    }
    s_r1[tid] = a1; s_r2[tid] = a2;
    __syncthreads();
    for (int s = 128; s >= 32; s >>= 1) {
        if (tid < s) { add4(s_r1[tid], s_r1[tid+s]); add4(s_r2[tid], s_r2[tid+s]); }
        __syncthreads();
    }
    if (tid < 32) {
        float4 t1 = s_r1[tid], t2 = s_r2[tid];
        atomicAdd(&out[b*2*E_ + tid*4+0], t1.x);
        atomicAdd(&out[b*2*E_ + tid*4+1], t1.y);
        atomicAdd(&out[b*2*E_ + tid*4+2], t1.z);
        atomicAdd(&out[b*2*E_ + tid*4+3], t1.w);
        atomicAdd(&out[b*2*E_ + E_ + tid*4+0], t2.x);
        atomicAdd(&out[b*2*E_ + E_ + tid*4+1], t2.y);
        atomicAdd(&out[b*2*E_ + E_ + tid*4+2], t2.z);
        atomicAdd(&out[b*2*E_ + E_ + tid*4+3], t2.w);
    }
}

extern "C" void kernel_launch(void* const* d_in, const int* in_sizes, int n_in,
                              void* d_out, int out_size, void* d_ws, size_t ws_size,
                              hipStream_t stream) {
    const float* x1 = (const float*)d_in[0];
    const float* x2 = (const float*)d_in[1];
    const float* W1 = (const float*)d_in[2];
    const float* b1 = (const float*)d_in[3];
    const float* U1 = (const float*)d_in[4];
    const float* W2 = (const float*)d_in[5];
    const float* b2 = (const float*)d_in[6];
    const float* U2 = (const float*)d_in[7];
    float* ws  = (float*)d_ws;
    float* out = (float*)d_out;

    ka_gram<<<dim3(B_, NG), 512, 0, stream>>>(x1, x2, W1, b1, W2, b2, ws);
    kb_c<<<dim3(B_, 8), 256, 0, stream>>>(ws);
    kc_etU<<<dim3(16, 2), 256, 0, stream>>>(U1, U2, ws);
    kd_softmax<<<dim3(B_, 2), 512, 0, stream>>>(ws, out);
    ke_out<<<dim3(B_, 16), 256, 0, stream>>>(x1, x2, ws, out);
}

// Round 5
// 193.229 us; speedup vs baseline: 2.4850x; 2.4850x over previous
//
#include <hip/hip_runtime.h>

// B=32, T=2048, E=128, fp32. Gram restructure, v3.1 (spill fix):
//   KA: 512 thr/block, 4x8 reg tile, BK=16 (8 barriers).
//   R4 lesson: __launch_bounds__(512,4) capped VGPR at 64 -> acc spilled ->
//   1.5GB scratch traffic, 371us. Fix: no min-wave hint (compiler ~120 VGPR),
//   and alias psx epilogue scratch onto sbuf (LDS 49->32.5KB) so 2 blocks/CU
//   still fit -> 4 waves/SIMD without the spill.
//   KB: one block per (b, 2 chunks): M read once, both c1/c2 partials.
//   KC: sums 8 c-partials on load; et += c.U (U read once). KD softmax. KE o-pass.

#define B_ 32
#define T_ 2048
#define E_ 128
#define EV (E_/4)
#define INV_T (1.0f/2048.0f)
#define RC 128      // rows per KA block
#define BK 16       // k-step rows
#define NSTEP (RC/BK)
#define NG (T_/RC)  // 16 chunks

// ws float offsets (every slot written before read -> no zeroing needed)
#define WS_PSX1 0                      // B*NG*E = 65536
#define WS_PSX2 65536                  // B*NG*E
#define WS_PM   131072                 // B*NG*E*E = 8388608 (33.5MB)
#define WS_ET1  8519680                // B*T
#define WS_ET2  8585216                // B*T
#define WS_C1   8650752                // B*8*E = 32768 (8-way partials)
#define WS_C2   8683520                // B*8*E

__device__ __forceinline__ float dot4(float4 a, float4 b) {
    return a.x*b.x + a.y*b.y + a.z*b.z + a.w*b.w;
}
__device__ __forceinline__ void fma4(float4& a, float s, const float4 v) {
    a.x += s*v.x; a.y += s*v.y; a.z += s*v.z; a.w += s*v.w;
}
__device__ __forceinline__ void add4(float4& a, const float4 v) {
    a.x += v.x; a.y += v.y; a.z += v.z; a.w += v.w;
}

// ---- KA: Gram partial + psx partial + xw logit base, one x pass ----
__global__ __launch_bounds__(512)
void ka_gram(const float* __restrict__ x1, const float* __restrict__ x2,
             const float* __restrict__ W1, const float* __restrict__ b1,
             const float* __restrict__ W2, const float* __restrict__ b2,
             float* __restrict__ ws) {
    __shared__ float4 sbuf[2][2][BK][32];   // [dbuf][tensor][row][swz slot] 32KB
    __shared__ float4 sW[2][32];
    float4* spx = &sbuf[0][0][0][0];        // epilogue alias (sbuf dead by then)
    const int b = blockIdx.x, g = blockIdx.y, tid = threadIdx.x;
    if (tid < 64) sW[tid>>5][tid&31] = ((const float4*)((tid<32) ? W1 : W2))[tid&31];
    __syncthreads();   // sW visible to ALL waves before prologue xw dot

    // staging role: tensor / row-in-chunk(16) / col-pair(16)
    const int ten = tid>>8, rem = tid&255, row = rem>>4, q = rem&15;
    // compute role: 4x8 tile at (e=ty*4.., f=tx*8..)
    const int ty = tid>>4, tx = tid&15;
    const int sA = (ty>>1) | ((ty&1)<<4);   // swizzled slot of logical c4=ty

    const float4* xg = (const float4*)(ten ? x2 : x1) + ((size_t)b*T_ + g*RC)*EV;
    const int loff = row*EV + 2*q;          // per-step load offset (float4)

    float* etp = ws + (ten ? WS_ET2 : WS_ET1) + (size_t)b*T_;
    const float* bias = ten ? b2 : b1;

    float4 acc[8];
    #pragma unroll
    for (int i = 0; i < 8; ++i) acc[i] = make_float4(0.f,0.f,0.f,0.f);
    float4 psa = {0,0,0,0}, psb = {0,0,0,0};

    // prologue: chunk 0 -> sbuf[0], plus its psx/xw
    {
        float4 n0 = xg[loff], n1 = xg[loff + 1];
        add4(psa, n0); add4(psb, n1);
        float d = dot4(n0, sW[ten][2*q]) + dot4(n1, sW[ten][2*q+1]);
        d += __shfl_xor(d, 1); d += __shfl_xor(d, 2);
        d += __shfl_xor(d, 4); d += __shfl_xor(d, 8);
        if (q == 0) { int t = g*RC + row; etp[t] = d + bias[t]; }
        sbuf[0][ten][row][q]      = n0;     // swz(2q)=q
        sbuf[0][ten][row][16 + q] = n1;     // swz(2q+1)=16+q
    }
    __syncthreads();

    for (int k = 0; k < NSTEP; ++k) {
        const int p = k & 1;
        float4 m0, m1;
        if (k < NSTEP-1) {
            m0 = xg[(k+1)*BK*EV + loff];
            m1 = xg[(k+1)*BK*EV + loff + 1];
        }
        #pragma unroll
        for (int t = 0; t < BK; ++t) {
            const float4 a   = sbuf[p][1][t][sA];        // x2 e-frag (4 rows)
            const float4 bv0 = sbuf[p][0][t][tx];        // x1 f-frag lo
            const float4 bv1 = sbuf[p][0][t][16 + tx];   // x1 f-frag hi
            fma4(acc[0], a.x, bv0); fma4(acc[1], a.x, bv1);
            fma4(acc[2], a.y, bv0); fma4(acc[3], a.y, bv1);
            fma4(acc[4], a.z, bv0); fma4(acc[5], a.z, bv1);
            fma4(acc[6], a.w, bv0); fma4(acc[7], a.w, bv1);
        }
        if (k < NSTEP-1) {
            add4(psa, m0); add4(psb, m1);
            float d = dot4(m0, sW[ten][2*q]) + dot4(m1, sW[ten][2*q+1]);
            d += __shfl_xor(d, 1); d += __shfl_xor(d, 2);
            d += __shfl_xor(d, 4); d += __shfl_xor(d, 8);
            if (q == 0) { int t = g*RC + (k+1)*BK + row; etp[t] = d + bias[t]; }
            sbuf[1-p][ten][row][q]      = m0;
            sbuf[1-p][ten][row][16 + q] = m1;
        }
        __syncthreads();
    }

    // M partial: logical layout [e][f4], e row stride 32 float4
    float4* pMW = (float4*)(ws + WS_PM) + (size_t)(b*NG + g)*4096;
    #pragma unroll
    for (int i = 0; i < 4; ++i) {
        pMW[(ty*4 + i)*32 + 2*tx + 0] = acc[2*i+0];
        pMW[(ty*4 + i)*32 + 2*tx + 1] = acc[2*i+1];
    }

    // psx partial: reduce over the 16 row-owners per (tensor, col-quad).
    // spx aliases sbuf — all sbuf reads are behind the loop's final barrier.
    spx[tid] = psa; spx[512 + tid] = psb;
    __syncthreads();
    if (tid < 64) {
        const int t2 = tid>>5, j = tid&31;
        const int base = (j&1)*512 + t2*256 + (j>>1);
        float4 s = {0,0,0,0};
        #pragma unroll
        for (int r = 0; r < 16; ++r) add4(s, spx[base + r*16]);
        ((float4*)(ws + (t2 ? WS_PSX2 : WS_PSX1)))[(size_t)(b*NG + g)*32 + j] = s;
    }
}

// ---- KB: sx reduce + per-2-chunk partials of BOTH c1 (M.sx2) and c2 (M^T.sx1).
//      M partials read exactly once. grid (B, 8). ----
__global__ __launch_bounds__(256)
void kb_c(float* __restrict__ ws) {
    __shared__ float4 ssx1v[32], ssx2v[32];
    __shared__ float4 c2p[8][32];
    const int b = blockIdx.x, gs = blockIdx.y, tid = threadIdx.x;
    float* ssx1 = (float*)ssx1v;
    float* ssx2 = (float*)ssx2v;
    if (tid < 128) {
        float s = 0.f;
        #pragma unroll
        for (int g = 0; g < NG; ++g) s += ws[WS_PSX2 + (size_t)(b*NG + g)*E_ + tid];
        ssx2[tid] = s;
    } else {
        float s = 0.f;
        #pragma unroll
        for (int g = 0; g < NG; ++g) s += ws[WS_PSX1 + (size_t)(b*NG + g)*E_ + (tid-128)];
        ssx1[tid-128] = s;
    }
    __syncthreads();
    const int hw = tid>>5, j = tid&31;
    const float4* pM4 = (const float4*)(ws + WS_PM) + (size_t)b*NG*4096;
    const float4 sxj = ssx2v[j];
    float4 c2a = {0,0,0,0};
    #pragma unroll
    for (int r = 0; r < 16; ++r) {
        const int e = hw*16 + r;
        const float s1 = ssx1[e];
        float ca = 0.f;
        #pragma unroll
        for (int g2 = 0; g2 < 2; ++g2) {
            float4 v = pM4[(size_t)(gs*2 + g2)*4096 + e*32 + j];
            ca += dot4(v, sxj);
            fma4(c2a, s1, v);
        }
        #pragma unroll
        for (int m = 1; m <= 16; m <<= 1) ca += __shfl_xor(ca, m);
        if (j == 0) ws[WS_C1 + (size_t)(b*8 + gs)*E_ + e] = ca * INV_T;
    }
    c2p[hw][j] = c2a;
    __syncthreads();
    if (tid < 128) {
        float s = 0.f;
        #pragma unroll
        for (int h = 0; h < 8; ++h) s += ((const float*)c2p)[h*128 + tid];
        ws[WS_C2 + (size_t)(b*8 + gs)*E_ + tid] = s * INV_T;
    }
}

// ---- KC: et += c.U, t-chunked (128 t / block); c = sum of 8 partials, in LDS ----
__global__ __launch_bounds__(256)
void kc_etU(const float* __restrict__ U1, const float* __restrict__ U2,
            float* __restrict__ ws) {
    __shared__ float s_c[B_][E_];          // 16 KB
    const int ch = blockIdx.x, sel = blockIdx.y, tid = threadIdx.x;
    const float4* c4g = (const float4*)(ws + (sel ? WS_C2 : WS_C1));
    float4* s_c4 = (float4*)&s_c[0][0];
    #pragma unroll
    for (int i = 0; i < 4; ++i) {
        const int idx = tid + 256*i;              // b*32 + e4
        const int base = (idx & ~31)*8 + (idx & 31);   // b*256 + e4
        float4 s = {0,0,0,0};
        #pragma unroll
        for (int gs = 0; gs < 8; ++gs) add4(s, c4g[base + gs*32]);
        s_c4[idx] = s;
    }
    __syncthreads();
    const float4* U4 = (const float4*)(sel ? U2 : U1);   // E x T/4
    const int c4i = tid&31, bg = tid>>5;                 // 8 groups of 4 batches
    float4 acc[4];
    #pragma unroll
    for (int q = 0; q < 4; ++q) acc[q] = make_float4(0.f,0.f,0.f,0.f);
    #pragma unroll 4
    for (int e = 0; e < E_; ++e) {
        const float4 u = U4[(size_t)e*(T_/4) + ch*32 + c4i];
        fma4(acc[0], s_c[bg*4+0][e], u);
        fma4(acc[1], s_c[bg*4+1][e], u);
        fma4(acc[2], s_c[bg*4+2][e], u);
        fma4(acc[3], s_c[bg*4+3][e], u);
    }
    float4* et4 = (float4*)(ws + (sel ? WS_ET2 : WS_ET1));
    #pragma unroll
    for (int q = 0; q < 4; ++q) {
        const int bb = bg*4 + q;
        const size_t idx = (size_t)bb*(T_/4) + ch*32 + c4i;
        float4 v = et4[idx];          // xw base from KA
        add4(v, acc[q]);
        et4[idx] = v;
    }
}

// ---- KD: softmax over t -> probs in place; zero out for KE's atomics ----
__global__ __launch_bounds__(512)
void kd_softmax(float* __restrict__ ws, float* __restrict__ out) {
    __shared__ float red[512];
    const int b = blockIdx.x, sel = blockIdx.y, tid = threadIdx.x;
    float4* et4 = (float4*)(ws + (sel ? WS_ET2 : WS_ET1) + (size_t)b*T_);
    float4 v = et4[tid];
    if (tid < E_) out[b*2*E_ + sel*E_ + tid] = 0.f;
    float m = fmaxf(fmaxf(v.x, v.y), fmaxf(v.z, v.w));
    red[tid] = m; __syncthreads();
    for (int s = 256; s > 0; s >>= 1) {
        if (tid < s) red[tid] = fmaxf(red[tid], red[tid+s]);
        __syncthreads();
    }
    m = red[0]; __syncthreads();
    float4 e4;
    e4.x = __expf(v.x - m); e4.y = __expf(v.y - m);
    e4.z = __expf(v.z - m); e4.w = __expf(v.w - m);
    red[tid] = e4.x + e4.y + e4.z + e4.w;
    __syncthreads();
    for (int s = 256; s > 0; s >>= 1) {
        if (tid < s) red[tid] += red[tid+s];
        __syncthreads();
    }
    const float il = 1.f / red[0];
    e4.x *= il; e4.y *= il; e4.z *= il; e4.w *= il;
    et4[tid] = e4;
}

// ---- KE: o = sum_t at[t]*x[t,:] (proven) ----
__global__ __launch_bounds__(256)
void ke_out(const float* __restrict__ x1, const float* __restrict__ x2,
            const float* __restrict__ ws, float* __restrict__ out) {
    __shared__ float4 s_r1[256], s_r2[256];
    __shared__ float s_p1[128], s_p2[128];
    const int b = blockIdx.x, g = blockIdx.y, tid = threadIdx.x;
    const float* pr1 = ws + WS_ET1 + (size_t)b*T_ + g*128;
    const float* pr2 = ws + WS_ET2 + (size_t)b*T_ + g*128;
    if (tid < 128) s_p1[tid] = pr1[tid];
    else           s_p2[tid - 128] = pr2[tid - 128];
    __syncthreads();
    const float4* p1 = (const float4*)x1 + ((size_t)b*T_ + g*128)*EV;
    const float4* p2 = (const float4*)x2 + ((size_t)b*T_ + g*128)*EV;
    const int rg = tid >> 5, q = tid & 31;
    float4 a1 = {0,0,0,0}, a2 = {0,0,0,0};
    #pragma unroll
    for (int i = 0; i < 16; ++i) {
        int r = i*8 + rg;
        fma4(a1, s_p1[r], p1[r*EV + q]);
        fma4(a2, s_p2[r], p2[r*EV + q]);
    }
    s_r1[tid] = a1; s_r2[tid] = a2;
    __syncthreads();
    for (int s = 128; s >= 32; s >>= 1) {
        if (tid < s) { add4(s_r1[tid], s_r1[tid+s]); add4(s_r2[tid], s_r2[tid+s]); }
        __syncthreads();
    }
    if (tid < 32) {
        float4 t1 = s_r1[tid], t2 = s_r2[tid];
        atomicAdd(&out[b*2*E_ + tid*4+0], t1.x);
        atomicAdd(&out[b*2*E_ + tid*4+1], t1.y);
        atomicAdd(&out[b*2*E_ + tid*4+2], t1.z);
        atomicAdd(&out[b*2*E_ + tid*4+3], t1.w);
        atomicAdd(&out[b*2*E_ + E_ + tid*4+0], t2.x);
        atomicAdd(&out[b*2*E_ + E_ + tid*4+1], t2.y);
        atomicAdd(&out[b*2*E_ + E_ + tid*4+2], t2.z);
        atomicAdd(&out[b*2*E_ + E_ + tid*4+3], t2.w);
    }
}

extern "C" void kernel_launch(void* const* d_in, const int* in_sizes, int n_in,
                              void* d_out, int out_size, void* d_ws, size_t ws_size,
                              hipStream_t stream) {
    const float* x1 = (const float*)d_in[0];
    const float* x2 = (const float*)d_in[1];
    const float* W1 = (const float*)d_in[2];
    const float* b1 = (const float*)d_in[3];
    const float* U1 = (const float*)d_in[4];
    const float* W2 = (const float*)d_in[5];
    const float* b2 = (const float*)d_in[6];
    const float* U2 = (const float*)d_in[7];
    float* ws  = (float*)d_ws;
    float* out = (float*)d_out;

    ka_gram<<<dim3(B_, NG), 512, 0, stream>>>(x1, x2, W1, b1, W2, b2, ws);
    kb_c<<<dim3(B_, 8), 256, 0, stream>>>(ws);
    kc_etU<<<dim3(16, 2), 256, 0, stream>>>(U1, U2, ws);
    kd_softmax<<<dim3(B_, 2), 512, 0, stream>>>(ws, out);
    ke_out<<<dim3(B_, 16), 256, 0, stream>>>(x1, x2, ws, out);
}

// Round 6
// 182.946 us; speedup vs baseline: 2.6247x; 1.0562x over previous
//
#include <hip/hip_runtime.h>

// B=32, T=2048, E=128, fp32. Gram restructure, v4 (fat-step KA):
//   R3 (BK=8 dbuf, 8x8) = 48.8us, R5 (BK=16 dbuf, 4x8) = 64.5us — both ~30%
//   VALU: 16 barrier-separated steps each drain a ~900cy global prefetch with
//   only 2-4 waves/SIMD. v4: BK=64 SINGLE buffer, 2 steps, 4 barriers total.
//   Compute per step (~16K cyc/wave) >> HBM latency; 2 blocks/CU dephase.
//   8x8 tile (proven best reuse), verified swizzled slots (q <-> c4 2q).
//   KB (B,8): M read once, both c1/c2 partials. KC: U read once. KD. KE.

#define B_ 32
#define T_ 2048
#define E_ 128
#define EV (E_/4)
#define INV_T (1.0f/2048.0f)
#define RC 128      // rows per KA block
#define NG (T_/RC)  // 16 chunks

// ws float offsets (every slot written before read -> no zeroing needed)
#define WS_PSX1 0                      // B*NG*E = 65536
#define WS_PSX2 65536                  // B*NG*E
#define WS_PM   131072                 // B*NG*E*E = 8388608 (33.5MB)
#define WS_ET1  8519680                // B*T
#define WS_ET2  8585216                // B*T
#define WS_C1   8650752                // B*8*E = 32768 (8-way partials)
#define WS_C2   8683520                // B*8*E

__device__ __forceinline__ float dot4(float4 a, float4 b) {
    return a.x*b.x + a.y*b.y + a.z*b.z + a.w*b.w;
}
__device__ __forceinline__ void fma4(float4& a, float s, const float4 v) {
    a.x += s*v.x; a.y += s*v.y; a.z += s*v.z; a.w += s*v.w;
}
__device__ __forceinline__ void add4(float4& a, const float4 v) {
    a.x += v.x; a.y += v.y; a.z += v.z; a.w += v.w;
}

// ---- KA: Gram partial + psx partial + xw logit base, one x pass ----
__global__ __launch_bounds__(256)
void ka_gram(const float* __restrict__ x1, const float* __restrict__ x2,
             const float* __restrict__ W1, const float* __restrict__ b1,
             const float* __restrict__ W2, const float* __restrict__ b2,
             float* __restrict__ ws) {
    __shared__ float4 sb[2][64][32];    // [tensor][row][swz slot] 64KB
    __shared__ float4 sW[2][32];
    const int b = blockIdx.x, g = blockIdx.y, tid = threadIdx.x;
    if (tid < 64) sW[tid>>5][tid&31] = ((const float4*)((tid<32) ? W1 : W2))[tid&31];
    __syncthreads();

    const int q = tid & 15, rr = tid >> 4;   // staging: col-pair q, row-group rr
    const int ty = tid >> 4, tx = tid & 15;  // compute: 8x8 tile (e=8ty.., f=8tx..)

    const float4* x1g = (const float4*)x1 + ((size_t)b*T_ + g*RC)*EV;
    const float4* x2g = (const float4*)x2 + ((size_t)b*T_ + g*RC)*EV;

    float4 acc[16];
    #pragma unroll
    for (int i = 0; i < 16; ++i) acc[i] = make_float4(0.f,0.f,0.f,0.f);
    float4 ps[4];   // x1 c4=2q, x1 c4=2q+1, x2 c4=2q, x2 c4=2q+1
    #pragma unroll
    for (int i = 0; i < 4; ++i) ps[i] = make_float4(0.f,0.f,0.f,0.f);

    for (int s = 0; s < 2; ++s) {
        // ---- stage rows s*64 .. s*64+63 of both tensors; psx+xw en route ----
        #pragma unroll
        for (int ten = 0; ten < 2; ++ten) {
            const float4* xg = ten ? x2g : x1g;
            float* etp = ws + (ten ? WS_ET2 : WS_ET1) + (size_t)b*T_;
            const float* bias = ten ? b2 : b1;
            #pragma unroll
            for (int i = 0; i < 4; ++i) {
                const int row = rr + i*16;               // row within step
                const float4* p = xg + (size_t)(s*64 + row)*EV + 2*q;
                const float4 n0 = p[0], n1 = p[1];
                add4(ps[ten*2+0], n0); add4(ps[ten*2+1], n1);
                float d = dot4(n0, sW[ten][2*q]) + dot4(n1, sW[ten][2*q+1]);
                d += __shfl_xor(d, 1); d += __shfl_xor(d, 2);
                d += __shfl_xor(d, 4); d += __shfl_xor(d, 8);
                if (q == 0) {
                    const int t = g*RC + s*64 + row;
                    etp[t] = d + bias[t];
                }
                sb[ten][row][q]      = n0;   // slot q      <-> c4 2q
                sb[ten][row][16 + q] = n1;   // slot 16+q   <-> c4 2q+1
            }
        }
        __syncthreads();
        // ---- Gram rank-64 update: M[8ty+i][8tx..8tx+7] ----
        #pragma unroll 8
        for (int t = 0; t < 64; ++t) {
            const float4 a0  = sb[1][t][ty];        // x2 e = 8ty..8ty+3
            const float4 a1  = sb[1][t][16 + ty];   // x2 e = 8ty+4..8ty+7
            const float4 bv0 = sb[0][t][tx];        // x1 f = 8tx..8tx+3
            const float4 bv1 = sb[0][t][16 + tx];   // x1 f = 8tx+4..8tx+7
            const float ae[8] = {a0.x,a0.y,a0.z,a0.w,a1.x,a1.y,a1.z,a1.w};
            #pragma unroll
            for (int i = 0; i < 8; ++i) {
                fma4(acc[2*i+0], ae[i], bv0);
                fma4(acc[2*i+1], ae[i], bv1);
            }
        }
        __syncthreads();
    }

    // M partial: logical layout [e][f4], e row stride 32 float4 (verified map)
    float4* pMW = (float4*)(ws + WS_PM) + (size_t)(b*NG + g)*4096;
    #pragma unroll
    for (int i = 0; i < 8; ++i) {
        pMW[(ty*8 + i)*32 + 2*tx + 0] = acc[2*i+0];
        pMW[(ty*8 + i)*32 + 2*tx + 1] = acc[2*i+1];
    }

    // psx partial: reduce the 16 row-groups per (tensor, col-quad); sb is dead.
    float4* spx = &sb[0][0][0];
    spx[tid] = ps[0]; spx[256 + tid] = ps[1];
    spx[512 + tid] = ps[2]; spx[768 + tid] = ps[3];
    __syncthreads();
    if (tid < 64) {
        const int pt = tid>>5, c4 = tid&31, qq = c4>>1, h = c4&1;
        float4 sum = {0,0,0,0};
        #pragma unroll
        for (int r = 0; r < 16; ++r) add4(sum, spx[pt*512 + h*256 + r*16 + qq]);
        ((float4*)(ws + (pt ? WS_PSX2 : WS_PSX1)))[(size_t)(b*NG + g)*32 + c4] = sum;
    }
}

// ---- KB: sx reduce + per-2-chunk partials of BOTH c1 (M.sx2) and c2 (M^T.sx1).
//      M partials read exactly once. grid (B, 8). ----
__global__ __launch_bounds__(256)
void kb_c(float* __restrict__ ws) {
    __shared__ float4 ssx1v[32], ssx2v[32];
    __shared__ float4 c2p[8][32];
    const int b = blockIdx.x, gs = blockIdx.y, tid = threadIdx.x;
    float* ssx1 = (float*)ssx1v;
    float* ssx2 = (float*)ssx2v;
    if (tid < 128) {
        float s = 0.f;
        #pragma unroll
        for (int g = 0; g < NG; ++g) s += ws[WS_PSX2 + (size_t)(b*NG + g)*E_ + tid];
        ssx2[tid] = s;
    } else {
        float s = 0.f;
        #pragma unroll
        for (int g = 0; g < NG; ++g) s += ws[WS_PSX1 + (size_t)(b*NG + g)*E_ + (tid-128)];
        ssx1[tid-128] = s;
    }
    __syncthreads();
    const int hw = tid>>5, j = tid&31;
    const float4* pM4 = (const float4*)(ws + WS_PM) + (size_t)b*NG*4096;
    const float4 sxj = ssx2v[j];
    float4 c2a = {0,0,0,0};
    #pragma unroll
    for (int r = 0; r < 16; ++r) {
        const int e = hw*16 + r;
        const float s1 = ssx1[e];
        float ca = 0.f;
        #pragma unroll
        for (int g2 = 0; g2 < 2; ++g2) {
            float4 v = pM4[(size_t)(gs*2 + g2)*4096 + e*32 + j];
            ca += dot4(v, sxj);
            fma4(c2a, s1, v);
        }
        #pragma unroll
        for (int m = 1; m <= 16; m <<= 1) ca += __shfl_xor(ca, m);
        if (j == 0) ws[WS_C1 + (size_t)(b*8 + gs)*E_ + e] = ca * INV_T;
    }
    c2p[hw][j] = c2a;
    __syncthreads();
    if (tid < 128) {
        float s = 0.f;
        #pragma unroll
        for (int h = 0; h < 8; ++h) s += ((const float*)c2p)[h*128 + tid];
        ws[WS_C2 + (size_t)(b*8 + gs)*E_ + tid] = s * INV_T;
    }
}

// ---- KC: et += c.U, t-chunked (128 t / block); c = sum of 8 partials, in LDS ----
__global__ __launch_bounds__(256)
void kc_etU(const float* __restrict__ U1, const float* __restrict__ U2,
            float* __restrict__ ws) {
    __shared__ float s_c[B_][E_];          // 16 KB
    const int ch = blockIdx.x, sel = blockIdx.y, tid = threadIdx.x;
    const float4* c4g = (const float4*)(ws + (sel ? WS_C2 : WS_C1));
    float4* s_c4 = (float4*)&s_c[0][0];
    #pragma unroll
    for (int i = 0; i < 4; ++i) {
        const int idx = tid + 256*i;              // b*32 + e4
        const int base = (idx & ~31)*8 + (idx & 31);   // b*256 + e4
        float4 s = {0,0,0,0};
        #pragma unroll
        for (int gs = 0; gs < 8; ++gs) add4(s, c4g[base + gs*32]);
        s_c4[idx] = s;
    }
    __syncthreads();
    const float4* U4 = (const float4*)(sel ? U2 : U1);   // E x T/4
    const int c4i = tid&31, bg = tid>>5;                 // 8 groups of 4 batches
    float4 acc[4];
    #pragma unroll
    for (int q = 0; q < 4; ++q) acc[q] = make_float4(0.f,0.f,0.f,0.f);
    #pragma unroll 4
    for (int e = 0; e < E_; ++e) {
        const float4 u = U4[(size_t)e*(T_/4) + ch*32 + c4i];
        fma4(acc[0], s_c[bg*4+0][e], u);
        fma4(acc[1], s_c[bg*4+1][e], u);
        fma4(acc[2], s_c[bg*4+2][e], u);
        fma4(acc[3], s_c[bg*4+3][e], u);
    }
    float4* et4 = (float4*)(ws + (sel ? WS_ET2 : WS_ET1));
    #pragma unroll
    for (int q = 0; q < 4; ++q) {
        const int bb = bg*4 + q;
        const size_t idx = (size_t)bb*(T_/4) + ch*32 + c4i;
        float4 v = et4[idx];          // xw base from KA
        add4(v, acc[q]);
        et4[idx] = v;
    }
}

// ---- KD: softmax over t -> probs in place; zero out for KE's atomics ----
__global__ __launch_bounds__(512)
void kd_softmax(float* __restrict__ ws, float* __restrict__ out) {
    __shared__ float red[512];
    const int b = blockIdx.x, sel = blockIdx.y, tid = threadIdx.x;
    float4* et4 = (float4*)(ws + (sel ? WS_ET2 : WS_ET1) + (size_t)b*T_);
    float4 v = et4[tid];
    if (tid < E_) out[b*2*E_ + sel*E_ + tid] = 0.f;
    float m = fmaxf(fmaxf(v.x, v.y), fmaxf(v.z, v.w));
    red[tid] = m; __syncthreads();
    for (int s = 256; s > 0; s >>= 1) {
        if (tid < s) red[tid] = fmaxf(red[tid], red[tid+s]);
        __syncthreads();
    }
    m = red[0]; __syncthreads();
    float4 e4;
    e4.x = __expf(v.x - m); e4.y = __expf(v.y - m);
    e4.z = __expf(v.z - m); e4.w = __expf(v.w - m);
    red[tid] = e4.x + e4.y + e4.z + e4.w;
    __syncthreads();
    for (int s = 256; s > 0; s >>= 1) {
        if (tid < s) red[tid] += red[tid+s];
        __syncthreads();
    }
    const float il = 1.f / red[0];
    e4.x *= il; e4.y *= il; e4.z *= il; e4.w *= il;
    et4[tid] = e4;
}

// ---- KE: o = sum_t at[t]*x[t,:] (proven) ----
__global__ __launch_bounds__(256)
void ke_out(const float* __restrict__ x1, const float* __restrict__ x2,
            const float* __restrict__ ws, float* __restrict__ out) {
    __shared__ float4 s_r1[256], s_r2[256];
    __shared__ float s_p1[128], s_p2[128];
    const int b = blockIdx.x, g = blockIdx.y, tid = threadIdx.x;
    const float* pr1 = ws + WS_ET1 + (size_t)b*T_ + g*128;
    const float* pr2 = ws + WS_ET2 + (size_t)b*T_ + g*128;
    if (tid < 128) s_p1[tid] = pr1[tid];
    else           s_p2[tid - 128] = pr2[tid - 128];
    __syncthreads();
    const float4* p1 = (const float4*)x1 + ((size_t)b*T_ + g*128)*EV;
    const float4* p2 = (const float4*)x2 + ((size_t)b*T_ + g*128)*EV;
    const int rg = tid >> 5, q = tid & 31;
    float4 a1 = {0,0,0,0}, a2 = {0,0,0,0};
    #pragma unroll
    for (int i = 0; i < 16; ++i) {
        int r = i*8 + rg;
        fma4(a1, s_p1[r], p1[r*EV + q]);
        fma4(a2, s_p2[r], p2[r*EV + q]);
    }
    s_r1[tid] = a1; s_r2[tid] = a2;
    __syncthreads();
    for (int s = 128; s >= 32; s >>= 1) {
        if (tid < s) { add4(s_r1[tid], s_r1[tid+s]); add4(s_r2[tid], s_r2[tid+s]); }
        __syncthreads();
    }
    if (tid < 32) {
        float4 t1 = s_r1[tid], t2 = s_r2[tid];
        atomicAdd(&out[b*2*E_ + tid*4+0], t1.x);
        atomicAdd(&out[b*2*E_ + tid*4+1], t1.y);
        atomicAdd(&out[b*2*E_ + tid*4+2], t1.z);
        atomicAdd(&out[b*2*E_ + tid*4+3], t1.w);
        atomicAdd(&out[b*2*E_ + E_ + tid*4+0], t2.x);
        atomicAdd(&out[b*2*E_ + E_ + tid*4+1], t2.y);
        atomicAdd(&out[b*2*E_ + E_ + tid*4+2], t2.z);
        atomicAdd(&out[b*2*E_ + E_ + tid*4+3], t2.w);
    }
}

extern "C" void kernel_launch(void* const* d_in, const int* in_sizes, int n_in,
                              void* d_out, int out_size, void* d_ws, size_t ws_size,
                              hipStream_t stream) {
    const float* x1 = (const float*)d_in[0];
    const float* x2 = (const float*)d_in[1];
    const float* W1 = (const float*)d_in[2];
    const float* b1 = (const float*)d_in[3];
    const float* U1 = (const float*)d_in[4];
    const float* W2 = (const float*)d_in[5];
    const float* b2 = (const float*)d_in[6];
    const float* U2 = (const float*)d_in[7];
    float* ws  = (float*)d_ws;
    float* out = (float*)d_out;

    ka_gram<<<dim3(B_, NG), 256, 0, stream>>>(x1, x2, W1, b1, W2, b2, ws);
    kb_c<<<dim3(B_, 8), 256, 0, stream>>>(ws);
    kc_etU<<<dim3(16, 2), 256, 0, stream>>>(U1, U2, ws);
    kd_softmax<<<dim3(B_, 2), 512, 0, stream>>>(ws, out);
    ke_out<<<dim3(B_, 16), 256, 0, stream>>>(x1, x2, ws, out);
}

// Round 7
// 165.407 us; speedup vs baseline: 2.9030x; 1.1060x over previous
//
#include <hip/hip_runtime.h>

// B=32, T=2048, E=128, fp32. Gram restructure, v5 (MFMA KA):
//   R3/R5/R6 VALU Gram all pinned at ~30% VALUBusy (LDS B/FLOP=1 vs 0.5 HW
//   ratio). v5 computes M = X2^T X1 on the MATRIX pipe: split-bf16
//   (x = hi + lo, trunc), 3 MFMA passes Hi2Hi1 + Hi2Lo1 + Lo2Hi1, fp32 acc.
//   A/B frags use IDENTICAL lane->t mapping => any k-sublayout assumption
//   error is a harmless relabeling of the contraction index.
//   LDS: 4 bufs [e=128][t=64] bf16 (t-transposed), XOR swizzle
//   (e&3)<<3 ^ ((e>>2)&3)<<5 -> b64 frag reads at structural minimum.
//   psx + x.W logits from fp32 prefetch regs (proven). KB/KC/KD/KE verbatim R6.

#define B_ 32
#define T_ 2048
#define E_ 128
#define EV (E_/4)
#define INV_T (1.0f/2048.0f)
#define RC 128      // rows per KA block
#define NG (T_/RC)  // 16 chunks

#define WS_PSX1 0                      // B*NG*E = 65536
#define WS_PSX2 65536                  // B*NG*E
#define WS_PM   131072                 // B*NG*E*E = 8388608 (33.5MB)
#define WS_ET1  8519680                // B*T
#define WS_ET2  8585216                // B*T
#define WS_C1   8650752                // B*8*E
#define WS_C2   8683520                // B*8*E

typedef __attribute__((ext_vector_type(8))) short short8;
typedef __attribute__((ext_vector_type(4))) float f32x4;

__device__ __forceinline__ float dot4(float4 a, float4 b) {
    return a.x*b.x + a.y*b.y + a.z*b.z + a.w*b.w;
}
__device__ __forceinline__ void fma4(float4& a, float s, const float4 v) {
    a.x += s*v.x; a.y += s*v.y; a.z += s*v.z; a.w += s*v.w;
}
__device__ __forceinline__ void add4(float4& a, const float4 v) {
    a.x += v.x; a.y += v.y; a.z += v.z; a.w += v.w;
}

__device__ __forceinline__ unsigned swz(int e, unsigned tbyte) {
    return tbyte ^ ((((unsigned)e & 3u) << 3) | ((((unsigned)e >> 2) & 3u) << 5));
}

// pack 4 consecutive-t fp32 for one e-row into hi/lo bf16 pair-words
__device__ __forceinline__ void pack_hilo(float f0, float f1, float f2, float f3,
                                          unsigned long long& wh,
                                          unsigned long long& wl) {
    unsigned u0 = __float_as_uint(f0), u1 = __float_as_uint(f1);
    unsigned u2 = __float_as_uint(f2), u3 = __float_as_uint(f3);
    unsigned h0 = u0 & 0xFFFF0000u, h1 = u1 & 0xFFFF0000u;
    unsigned h2 = u2 & 0xFFFF0000u, h3 = u3 & 0xFFFF0000u;
    unsigned hw0 = h1 | (h0 >> 16);
    unsigned hw1 = h3 | (h2 >> 16);
    unsigned l0 = __float_as_uint(f0 - __uint_as_float(h0));
    unsigned l1 = __float_as_uint(f1 - __uint_as_float(h1));
    unsigned l2 = __float_as_uint(f2 - __uint_as_float(h2));
    unsigned l3 = __float_as_uint(f3 - __uint_as_float(h3));
    unsigned lw0 = (l1 & 0xFFFF0000u) | (l0 >> 16);
    unsigned lw1 = (l3 & 0xFFFF0000u) | (l2 >> 16);
    wh = ((unsigned long long)hw1 << 32) | hw0;
    wl = ((unsigned long long)lw1 << 32) | lw0;
}

__device__ __forceinline__ short8 frag_ld(const char* buf, int row, int t0) {
    unsigned a1 = (unsigned)row * 128u + swz(row, (unsigned)t0 * 2u);
    union { unsigned long long u[2]; short8 v; } r;
    r.u[0] = *(const unsigned long long*)(buf + a1);
    r.u[1] = *(const unsigned long long*)(buf + (a1 ^ 32u));  // t0+16 block
    return r.v;
}

// ---- KA: Gram (MFMA split-bf16) + psx partial + xw logit base, one x pass ----
__global__ __launch_bounds__(256)
void ka_gram(const float* __restrict__ x1, const float* __restrict__ x2,
             const float* __restrict__ W1, const float* __restrict__ b1,
             const float* __restrict__ W2, const float* __restrict__ b2,
             float* __restrict__ ws) {
    __shared__ unsigned short ldsq[4][128][64];   // h1,l1,h2,l2 : 64 KB
    __shared__ float4 sW[2][32];
    const int b = blockIdx.x, g = blockIdx.y, tid = threadIdx.x;
    if (tid < 64) sW[tid>>5][tid&31] = ((const float4*)((tid<32) ? W1 : W2))[tid&31];
    __syncthreads();   // sW visible before first xw dot (R2 lesson)

    const int eq = tid & 31, tp = tid >> 5;       // staging role
    const int lane = tid & 63, w = tid >> 6;      // MFMA role: wave w owns e 32w..32w+31

    const float4* x1g = (const float4*)x1 + ((size_t)b*T_ + g*RC)*EV;
    const float4* x2g = (const float4*)x2 + ((size_t)b*T_ + g*RC)*EV;

    float4 psA1 = {0,0,0,0}, psA2 = {0,0,0,0};
    f32x4 acc[2][8];
    #pragma unroll
    for (int i = 0; i < 2; ++i)
        #pragma unroll
        for (int j = 0; j < 8; ++j) acc[i][j] = (f32x4){0.f,0.f,0.f,0.f};

    char* Lb = (char*)&ldsq[0][0][0];
    const char* Apass[3] = { Lb + 2*16384, Lb + 2*16384, Lb + 3*16384 };  // h2,h2,l2
    const char* Bpass[3] = { Lb + 0,       Lb + 1*16384, Lb + 0       };  // h1,l1,h1

    for (int s = 0; s < 2; ++s) {
        // ---- stage 64 t-rows of both tensors (fp32 -> hi/lo bf16, transposed) ----
        #pragma unroll
        for (int u = 0; u < 4; ++u) {
            const int ten = u >> 1;
            const int tq  = tp + (u & 1)*8;       // 0..15 t-quad within stage
            const int tl  = tq*4;                 // local t (0..63)
            const int tr  = s*64 + tl;            // t within chunk (0..127)
            const float4* src = (ten ? x2g : x1g) + (size_t)tr*EV + eq;
            const float4 v0 = src[0], v1 = src[EV], v2 = src[2*EV], v3 = src[3*EV];
            float4& ps = ten ? psA2 : psA1;
            add4(ps, v0); add4(ps, v1); add4(ps, v2); add4(ps, v3);
            const float4 wv = sW[ten][eq];
            float d0 = dot4(v0,wv), d1 = dot4(v1,wv), d2 = dot4(v2,wv), d3 = dot4(v3,wv);
            #pragma unroll
            for (int mm = 1; mm <= 16; mm <<= 1) {
                d0 += __shfl_xor(d0, mm); d1 += __shfl_xor(d1, mm);
                d2 += __shfl_xor(d2, mm); d3 += __shfl_xor(d3, mm);
            }
            if (eq == 0) {
                const int tg = g*RC + tr;
                const float4 bb = *(const float4*)((ten ? b2 : b1) + tg);
                *(float4*)(ws + (ten ? WS_ET2 : WS_ET1) + (size_t)b*T_ + tg)
                    = make_float4(d0+bb.x, d1+bb.y, d2+bb.z, d3+bb.w);
            }
            char* Hb = Lb + (ten ? 2 : 0)*16384;
            char* Lo = Hb + 16384;
            const unsigned tb = (unsigned)tl * 2u;
            unsigned long long wh, wl;
            {   const int e = eq*4 + 0; const unsigned off = (unsigned)e*128u + swz(e, tb);
                pack_hilo(v0.x, v1.x, v2.x, v3.x, wh, wl);
                *(unsigned long long*)(Hb + off) = wh;
                *(unsigned long long*)(Lo + off) = wl; }
            {   const int e = eq*4 + 1; const unsigned off = (unsigned)e*128u + swz(e, tb);
                pack_hilo(v0.y, v1.y, v2.y, v3.y, wh, wl);
                *(unsigned long long*)(Hb + off) = wh;
                *(unsigned long long*)(Lo + off) = wl; }
            {   const int e = eq*4 + 2; const unsigned off = (unsigned)e*128u + swz(e, tb);
                pack_hilo(v0.z, v1.z, v2.z, v3.z, wh, wl);
                *(unsigned long long*)(Hb + off) = wh;
                *(unsigned long long*)(Lo + off) = wl; }
            {   const int e = eq*4 + 3; const unsigned off = (unsigned)e*128u + swz(e, tb);
                pack_hilo(v0.w, v1.w, v2.w, v3.w, wh, wl);
                *(unsigned long long*)(Hb + off) = wh;
                *(unsigned long long*)(Lo + off) = wl; }
        }
        __syncthreads();
        // ---- MFMA: 3 passes x 2 k-steps; wave w: e-tiles {2w,2w+1}, f-tiles 0..7 ----
        #pragma unroll
        for (int pass = 0; pass < 3; ++pass) {
            #pragma unroll
            for (int ks = 0; ks < 2; ++ks) {
                const int t0 = ks*32 + ((lane>>4)<<2);
                const short8 a0 = frag_ld(Apass[pass], w*32 + (lane&15), t0);
                const short8 a1 = frag_ld(Apass[pass], w*32 + 16 + (lane&15), t0);
                #pragma unroll
                for (int ft = 0; ft < 8; ++ft) {
                    const short8 bv = frag_ld(Bpass[pass], ft*16 + (lane&15), t0);
                    acc[0][ft] = __builtin_amdgcn_mfma_f32_16x16x32_bf16(a0, bv, acc[0][ft], 0, 0, 0);
                    acc[1][ft] = __builtin_amdgcn_mfma_f32_16x16x32_bf16(a1, bv, acc[1][ft], 0, 0, 0);
                }
            }
        }
        __syncthreads();
    }

    // ---- M partial write: D layout col=lane&15 (=f), row=(lane>>4)*4+r (=e) [m89] ----
    float* pM = ws + WS_PM + (size_t)(b*NG + g)*16384;
    #pragma unroll
    for (int et = 0; et < 2; ++et) {
        #pragma unroll
        for (int ft = 0; ft < 8; ++ft) {
            #pragma unroll
            for (int r = 0; r < 4; ++r) {
                const int e = w*32 + et*16 + ((lane>>4)<<2) + r;
                const int f = ft*16 + (lane&15);
                pM[e*128 + f] = acc[et][ft][r];
            }
        }
    }

    // ---- psx partial: reduce 8 tp-owners per (tensor, e-quad); ldsq is dead ----
    float4* spx = (float4*)Lb;
    spx[tid*2 + 0] = psA1; spx[tid*2 + 1] = psA2;
    __syncthreads();
    if (tid < 64) {
        const int ten = tid>>5, eqq = tid&31;
        float4 sum = {0,0,0,0};
        #pragma unroll
        for (int t2 = 0; t2 < 8; ++t2) add4(sum, spx[(t2*32 + eqq)*2 + ten]);
        ((float4*)(ws + (ten ? WS_PSX2 : WS_PSX1)))[(size_t)(b*NG + g)*32 + eqq] = sum;
    }
}

// ---- KB: sx reduce + per-2-chunk partials of BOTH c1 (M.sx2) and c2 (M^T.sx1) ----
__global__ __launch_bounds__(256)
void kb_c(float* __restrict__ ws) {
    __shared__ float4 ssx1v[32], ssx2v[32];
    __shared__ float4 c2p[8][32];
    const int b = blockIdx.x, gs = blockIdx.y, tid = threadIdx.x;
    float* ssx1 = (float*)ssx1v;
    float* ssx2 = (float*)ssx2v;
    if (tid < 128) {
        float s = 0.f;
        #pragma unroll
        for (int g = 0; g < NG; ++g) s += ws[WS_PSX2 + (size_t)(b*NG + g)*E_ + tid];
        ssx2[tid] = s;
    } else {
        float s = 0.f;
        #pragma unroll
        for (int g = 0; g < NG; ++g) s += ws[WS_PSX1 + (size_t)(b*NG + g)*E_ + (tid-128)];
        ssx1[tid-128] = s;
    }
    __syncthreads();
    const int hw = tid>>5, j = tid&31;
    const float4* pM4 = (const float4*)(ws + WS_PM) + (size_t)b*NG*4096;
    const float4 sxj = ssx2v[j];
    float4 c2a = {0,0,0,0};
    #pragma unroll
    for (int r = 0; r < 16; ++r) {
        const int e = hw*16 + r;
        const float s1 = ssx1[e];
        float ca = 0.f;
        #pragma unroll
        for (int g2 = 0; g2 < 2; ++g2) {
            float4 v = pM4[(size_t)(gs*2 + g2)*4096 + e*32 + j];
            ca += dot4(v, sxj);
            fma4(c2a, s1, v);
        }
        #pragma unroll
        for (int m = 1; m <= 16; m <<= 1) ca += __shfl_xor(ca, m);
        if (j == 0) ws[WS_C1 + (size_t)(b*8 + gs)*E_ + e] = ca * INV_T;
    }
    c2p[hw][j] = c2a;
    __syncthreads();
    if (tid < 128) {
        float s = 0.f;
        #pragma unroll
        for (int h = 0; h < 8; ++h) s += ((const float*)c2p)[h*128 + tid];
        ws[WS_C2 + (size_t)(b*8 + gs)*E_ + tid] = s * INV_T;
    }
}

// ---- KC: et += c.U, t-chunked; c = sum of 8 partials, in LDS ----
__global__ __launch_bounds__(256)
void kc_etU(const float* __restrict__ U1, const float* __restrict__ U2,
            float* __restrict__ ws) {
    __shared__ float s_c[B_][E_];          // 16 KB
    const int ch = blockIdx.x, sel = blockIdx.y, tid = threadIdx.x;
    const float4* c4g = (const float4*)(ws + (sel ? WS_C2 : WS_C1));
    float4* s_c4 = (float4*)&s_c[0][0];
    #pragma unroll
    for (int i = 0; i < 4; ++i) {
        const int idx = tid + 256*i;                   // b*32 + e4
        const int base = (idx & ~31)*8 + (idx & 31);   // b*256 + e4
        float4 s = {0,0,0,0};
        #pragma unroll
        for (int gs = 0; gs < 8; ++gs) add4(s, c4g[base + gs*32]);
        s_c4[idx] = s;
    }
    __syncthreads();
    const float4* U4 = (const float4*)(sel ? U2 : U1);   // E x T/4
    const int c4i = tid&31, bg = tid>>5;
    float4 acc[4];
    #pragma unroll
    for (int q = 0; q < 4; ++q) acc[q] = make_float4(0.f,0.f,0.f,0.f);
    #pragma unroll 4
    for (int e = 0; e < E_; ++e) {
        const float4 u = U4[(size_t)e*(T_/4) + ch*32 + c4i];
        fma4(acc[0], s_c[bg*4+0][e], u);
        fma4(acc[1], s_c[bg*4+1][e], u);
        fma4(acc[2], s_c[bg*4+2][e], u);
        fma4(acc[3], s_c[bg*4+3][e], u);
    }
    float4* et4 = (float4*)(ws + (sel ? WS_ET2 : WS_ET1));
    #pragma unroll
    for (int q = 0; q < 4; ++q) {
        const int bb = bg*4 + q;
        const size_t idx = (size_t)bb*(T_/4) + ch*32 + c4i;
        float4 v = et4[idx];
        add4(v, acc[q]);
        et4[idx] = v;
    }
}

// ---- KD: softmax over t -> probs in place; zero out for KE's atomics ----
__global__ __launch_bounds__(512)
void kd_softmax(float* __restrict__ ws, float* __restrict__ out) {
    __shared__ float red[512];
    const int b = blockIdx.x, sel = blockIdx.y, tid = threadIdx.x;
    float4* et4 = (float4*)(ws + (sel ? WS_ET2 : WS_ET1) + (size_t)b*T_);
    float4 v = et4[tid];
    if (tid < E_) out[b*2*E_ + sel*E_ + tid] = 0.f;
    float m = fmaxf(fmaxf(v.x, v.y), fmaxf(v.z, v.w));
    red[tid] = m; __syncthreads();
    for (int s = 256; s > 0; s >>= 1) {
        if (tid < s) red[tid] = fmaxf(red[tid], red[tid+s]);
        __syncthreads();
    }
    m = red[0]; __syncthreads();
    float4 e4;
    e4.x = __expf(v.x - m); e4.y = __expf(v.y - m);
    e4.z = __expf(v.z - m); e4.w = __expf(v.w - m);
    red[tid] = e4.x + e4.y + e4.z + e4.w;
    __syncthreads();
    for (int s = 256; s > 0; s >>= 1) {
        if (tid < s) red[tid] += red[tid+s];
        __syncthreads();
    }
    const float il = 1.f / red[0];
    e4.x *= il; e4.y *= il; e4.z *= il; e4.w *= il;
    et4[tid] = e4;
}

// ---- KE: o = sum_t at[t]*x[t,:] (proven) ----
__global__ __launch_bounds__(256)
void ke_out(const float* __restrict__ x1, const float* __restrict__ x2,
            const float* __restrict__ ws, float* __restrict__ out) {
    __shared__ float4 s_r1[256], s_r2[256];
    __shared__ float s_p1[128], s_p2[128];
    const int b = blockIdx.x, g = blockIdx.y, tid = threadIdx.x;
    const float* pr1 = ws + WS_ET1 + (size_t)b*T_ + g*128;
    const float* pr2 = ws + WS_ET2 + (size_t)b*T_ + g*128;
    if (tid < 128) s_p1[tid] = pr1[tid];
    else           s_p2[tid - 128] = pr2[tid - 128];
    __syncthreads();
    const float4* p1 = (const float4*)x1 + ((size_t)b*T_ + g*128)*EV;
    const float4* p2 = (const float4*)x2 + ((size_t)b*T_ + g*128)*EV;
    const int rg = tid >> 5, q = tid & 31;
    float4 a1 = {0,0,0,0}, a2 = {0,0,0,0};
    #pragma unroll
    for (int i = 0; i < 16; ++i) {
        int r = i*8 + rg;
        fma4(a1, s_p1[r], p1[r*EV + q]);
        fma4(a2, s_p2[r], p2[r*EV + q]);
    }
    s_r1[tid] = a1; s_r2[tid] = a2;
    __syncthreads();
    for (int s = 128; s >= 32; s >>= 1) {
        if (tid < s) { add4(s_r1[tid], s_r1[tid+s]); add4(s_r2[tid], s_r2[tid+s]); }
        __syncthreads();
    }
    if (tid < 32) {
        float4 t1 = s_r1[tid], t2 = s_r2[tid];
        atomicAdd(&out[b*2*E_ + tid*4+0], t1.x);
        atomicAdd(&out[b*2*E_ + tid*4+1], t1.y);
        atomicAdd(&out[b*2*E_ + tid*4+2], t1.z);
        atomicAdd(&out[b*2*E_ + tid*4+3], t1.w);
        atomicAdd(&out[b*2*E_ + E_ + tid*4+0], t2.x);
        atomicAdd(&out[b*2*E_ + E_ + tid*4+1], t2.y);
        atomicAdd(&out[b*2*E_ + E_ + tid*4+2], t2.z);
        atomicAdd(&out[b*2*E_ + E_ + tid*4+3], t2.w);
    }
}

extern "C" void kernel_launch(void* const* d_in, const int* in_sizes, int n_in,
                              void* d_out, int out_size, void* d_ws, size_t ws_size,
                              hipStream_t stream) {
    const float* x1 = (const float*)d_in[0];
    const float* x2 = (const float*)d_in[1];
    const float* W1 = (const float*)d_in[2];
    const float* b1 = (const float*)d_in[3];
    const float* U1 = (const float*)d_in[4];
    const float* W2 = (const float*)d_in[5];
    const float* b2 = (const float*)d_in[6];
    const float* U2 = (const float*)d_in[7];
    float* ws  = (float*)d_ws;
    float* out = (float*)d_out;

    ka_gram<<<dim3(B_, NG), 256, 0, stream>>>(x1, x2, W1, b1, W2, b2, ws);
    kb_c<<<dim3(B_, 8), 256, 0, stream>>>(ws);
    kc_etU<<<dim3(16, 2), 256, 0, stream>>>(U1, U2, ws);
    kd_softmax<<<dim3(B_, 2), 512, 0, stream>>>(ws, out);
    ke_out<<<dim3(B_, 16), 256, 0, stream>>>(x1, x2, ws, out);
}